// Round 1
// baseline (101.449 us; speedup 1.0000x reference)
//
#include <hip/hip_runtime.h>
#include <hip/hip_bf16.h>
#include <stdint.h>

typedef __bf16 bf16x8 __attribute__((ext_vector_type(8)));
typedef float  f32x4  __attribute__((ext_vector_type(4)));

#define NROWS 16384
#define NFEAT 26
#define VOCAB 100000
#define DEMB  16
#define NINT  13
#define K1PAD 448

// ---------------- weight convert: W[K][N] fp32 -> Wt[N][Kpad] bf16 (zero-padded) ----
__global__ __launch_bounds__(256) void k_convW(const float* __restrict__ W,
                                               __bf16* __restrict__ Wt,
                                               int K, int N, int Kpad) {
  int i = blockIdx.x * 256 + threadIdx.x;
  if (i >= N * Kpad) return;
  int n = i / Kpad, k = i - n * Kpad;
  float v = (k < K) ? W[(size_t)k * N + n] : 0.f;
  Wt[i] = (__bf16)v;
}

// ---------------- gather + FM + linear + deep_in build ----------------
__global__ __launch_bounds__(256) void k_gather(
    const float* __restrict__ x_int,   // [B,13]
    const int*   __restrict__ x_cat,   // [B,26]
    const float* __restrict__ emb,     // [26,V,16]
    const float* __restrict__ lin,     // [26,V]
    const float* __restrict__ W_num,   // [13]
    const float* __restrict__ b_num,   // [1]
    const float* __restrict__ bias,    // [1]
    __bf16* __restrict__ deep_in,      // [B,448]
    float*  __restrict__ partial)      // [B]
{
  __shared__ int s_idx[16][NFEAT];
  const int t = threadIdx.x;
  const int row0 = blockIdx.x * 16;
  for (int i = t; i < 16 * NFEAT; i += 256) {
    int r = i / NFEAT, f = i - r * NFEAT;
    s_idx[r][f] = x_cat[(size_t)(row0 + r) * NFEAT + f];
  }
  __syncthreads();
  const int lr = t >> 4;       // local row 0..15
  const int d  = t & 15;       // embedding dim lane
  const int row = row0 + lr;

  float sum = 0.f, sumsq = 0.f;
  #pragma unroll
  for (int f = 0; f < NFEAT; ++f) {
    int idx = s_idx[lr][f];
    float e = emb[((size_t)f * VOCAB + idx) * DEMB + d];
    sum += e; sumsq += e * e;
    deep_in[(size_t)row * K1PAD + f * DEMB + d] = (__bf16)e;
  }
  float xv = (d < NINT) ? x_int[(size_t)row * NINT + d] : 0.f;
  deep_in[(size_t)row * K1PAD + 416 + d] = (__bf16)xv;
  deep_in[(size_t)row * K1PAD + 432 + d] = (__bf16)0.f;

  // linear (categorical): features d and d+16
  float lin_s = lin[(size_t)d * VOCAB + s_idx[lr][d]];
  if (d < NFEAT - 16) {
    int f2 = d + 16;
    lin_s += lin[(size_t)f2 * VOCAB + s_idx[lr][f2]];
  }
  float lin_num = (d < NINT) ? xv * W_num[d] : 0.f;
  float fm = 0.5f * (sum * sum - sumsq);

  float red = fm + lin_s + lin_num;
  #pragma unroll
  for (int off = 1; off < 16; off <<= 1)
    red += __shfl_xor(red, off, 16);
  if (d == 0) partial[row] = red + bias[0] + b_num[0];
}

// ---------------- GEMM + bias + ReLU (bf16 in, bf16 out, fp32 accum) ----------------
// A[M][K] row-major bf16, Bt[N][K] row-major bf16 (i.e. W^T), C[M][N] bf16.
template<int K, int N, int WM, int WN>
__global__ __launch_bounds__(256) void k_gemm(const __bf16* __restrict__ A,
                                              const __bf16* __restrict__ Bt,
                                              const float* __restrict__ bias,
                                              __bf16* __restrict__ C) {
  constexpr int BM = WM * 64, BN = WN * 64;
  constexpr int LDT = 40;  // padded LDS row stride (bf16): 80B -> 2-way bank alias (free)
  __shared__ __bf16 As[BM][LDT];
  __shared__ __bf16 Bs[BN][LDT];
  const int t = threadIdx.x;
  const int brow = blockIdx.x * BM, bcol = blockIdx.y * BN;
  const int w = t >> 6, lane = t & 63;
  const int wm = w % WM, wn = w / WM;
  const int lrow = lane & 15, kg = (lane >> 4) * 8;

  f32x4 acc[4][4];
  #pragma unroll
  for (int m = 0; m < 4; ++m)
    #pragma unroll
    for (int n = 0; n < 4; ++n)
      #pragma unroll
      for (int r = 0; r < 4; ++r) acc[m][n][r] = 0.f;

  for (int k0 = 0; k0 < K; k0 += 32) {
    #pragma unroll
    for (int c = t; c < BM * 4; c += 256) {
      int r = c >> 2, kc = (c & 3) * 8;
      *(f32x4*)(&As[r][kc]) = *(const f32x4*)(A + (size_t)(brow + r) * K + k0 + kc);
    }
    #pragma unroll
    for (int c = t; c < BN * 4; c += 256) {
      int r = c >> 2, kc = (c & 3) * 8;
      *(f32x4*)(&Bs[r][kc]) = *(const f32x4*)(Bt + (size_t)(bcol + r) * K + k0 + kc);
    }
    __syncthreads();
    bf16x8 af[4], bfr[4];
    #pragma unroll
    for (int m = 0; m < 4; ++m)
      af[m] = *(const bf16x8*)(&As[wm * 64 + m * 16 + lrow][kg]);
    #pragma unroll
    for (int n = 0; n < 4; ++n)
      bfr[n] = *(const bf16x8*)(&Bs[wn * 64 + n * 16 + lrow][kg]);
    #pragma unroll
    for (int m = 0; m < 4; ++m)
      #pragma unroll
      for (int n = 0; n < 4; ++n)
        acc[m][n] = __builtin_amdgcn_mfma_f32_16x16x32_bf16(af[m], bfr[n], acc[m][n], 0, 0, 0);
    __syncthreads();
  }

  #pragma unroll
  for (int n = 0; n < 4; ++n) {
    int col = bcol + wn * 64 + n * 16 + lrow;
    float bv = bias[col];
    #pragma unroll
    for (int m = 0; m < 4; ++m) {
      #pragma unroll
      for (int r = 0; r < 4; ++r) {
        int rowg = brow + wm * 64 + m * 16 + (lane >> 4) * 4 + r;
        float v = acc[m][n][r] + bv;
        v = fmaxf(v, 0.f);
        C[(size_t)rowg * N + col] = (__bf16)v;
      }
    }
  }
}

// ---------------- final 64->1 dot + combine ----------------
__global__ __launch_bounds__(256) void k_final(const __bf16* __restrict__ h4, // [B,64]
                                               const float* __restrict__ W5,  // [64]
                                               const float* __restrict__ b5,  // [1]
                                               const float* __restrict__ partial,
                                               float* __restrict__ out) {
  __shared__ float w[64];
  if (threadIdx.x < 64) w[threadIdx.x] = W5[threadIdx.x];
  __syncthreads();
  int row = blockIdx.x * 256 + threadIdx.x;
  const bf16x8* hv = (const bf16x8*)(h4 + (size_t)row * 64);
  float s = 0.f;
  #pragma unroll
  for (int j = 0; j < 8; ++j) {
    bf16x8 v = hv[j];
    #pragma unroll
    for (int i = 0; i < 8; ++i) s += (float)v[i] * w[j * 8 + i];
  }
  out[row] = s + b5[0] + partial[row];
}

extern "C" void kernel_launch(void* const* d_in, const int* in_sizes, int n_in,
                              void* d_out, int out_size, void* d_ws, size_t ws_size,
                              hipStream_t stream) {
  const float* x_int = (const float*)d_in[0];
  const int*   x_cat = (const int*)d_in[1];
  const float* emb   = (const float*)d_in[2];
  const float* lin   = (const float*)d_in[3];
  const float* W_num = (const float*)d_in[4];
  const float* b_num = (const float*)d_in[5];
  const float* bias  = (const float*)d_in[6];
  const float* W1 = (const float*)d_in[7];  const float* b1 = (const float*)d_in[8];
  const float* W2 = (const float*)d_in[9];  const float* b2 = (const float*)d_in[10];
  const float* W3 = (const float*)d_in[11]; const float* b3 = (const float*)d_in[12];
  const float* W4 = (const float*)d_in[13]; const float* b4 = (const float*)d_in[14];
  const float* W5 = (const float*)d_in[15]; const float* b5 = (const float*)d_in[16];
  float* out = (float*)d_out;

  char* ws = (char*)d_ws;
  size_t off = 0;
  __bf16* R0 = (__bf16*)(ws + off); off += 14680064;  // deep_in[16384][448] -> h2 -> h4
  __bf16* R1 = (__bf16*)(ws + off); off += 16777216;  // h1[16384][512] -> h3
  float* partial = (float*)(ws + off); off += 65536;
  __bf16* Wt1 = (__bf16*)(ws + off); off += 458752;   // [512][448]
  __bf16* Wt2 = (__bf16*)(ws + off); off += 262144;   // [256][512]
  __bf16* Wt3 = (__bf16*)(ws + off); off += 65536;    // [128][256]
  __bf16* Wt4 = (__bf16*)(ws + off); off += 16384;    // [64][128]

  k_convW<<<(512 * 448 + 255) / 256, 256, 0, stream>>>(W1, Wt1, 429, 512, 448);
  k_convW<<<(256 * 512 + 255) / 256, 256, 0, stream>>>(W2, Wt2, 512, 256, 512);
  k_convW<<<(128 * 256 + 255) / 256, 256, 0, stream>>>(W3, Wt3, 256, 128, 256);
  k_convW<<<(64 * 128 + 255) / 256, 256, 0, stream>>>(W4, Wt4, 128, 64, 128);

  k_gather<<<NROWS / 16, 256, 0, stream>>>(x_int, x_cat, emb, lin, W_num, b_num, bias,
                                           R0, partial);

  k_gemm<448, 512, 2, 2><<<dim3(NROWS / 128, 4), 256, 0, stream>>>(R0, Wt1, b1, R1);
  __bf16* h2 = R0;
  k_gemm<512, 256, 2, 2><<<dim3(NROWS / 128, 2), 256, 0, stream>>>(R1, Wt2, b2, h2);
  __bf16* h3 = R1;
  k_gemm<256, 128, 2, 2><<<dim3(NROWS / 128, 1), 256, 0, stream>>>(h2, Wt3, b3, h3);
  __bf16* h4 = R0;
  k_gemm<128, 64, 4, 1><<<dim3(NROWS / 256, 1), 256, 0, stream>>>(h3, Wt4, b4, h4);

  k_final<<<NROWS / 256, 256, 0, stream>>>(h4, W5, b5, partial, out);
}

// Round 2
// 52.973 us; speedup vs baseline: 1.9151x; 1.9151x over previous
//
#include <hip/hip_runtime.h>
#include <hip/hip_bf16.h>
#include <stdint.h>

typedef __bf16 bf16x8 __attribute__((ext_vector_type(8)));
typedef float  f32x4  __attribute__((ext_vector_type(4)));

#define NROWS 16384
#define NFEAT 26
#define VOCAB 100000

// ---------------- one-shot weight convert: W[K][N] fp32 -> Wt[N][Kpad] bf16 ----------
__device__ __forceinline__ void convW(const float* __restrict__ W, __bf16* __restrict__ Wt,
                                      int K, int N, int Kpad, int i) {
  int n = i / Kpad, k = i - n * Kpad;
  float v = (k < K) ? W[(size_t)k * N + n] : 0.f;
  Wt[i] = (__bf16)v;
}

__global__ __launch_bounds__(256) void k_convAll(
    const float* __restrict__ W1, const float* __restrict__ W2,
    const float* __restrict__ W3, const float* __restrict__ W4,
    __bf16* __restrict__ Wt1, __bf16* __restrict__ Wt2,
    __bf16* __restrict__ Wt3, __bf16* __restrict__ Wt4) {
  int i = blockIdx.x * 256 + threadIdx.x;
  if (i < 229376)          convW(W1, Wt1, 429, 512, 448, i);
  else if (i < 360448)     convW(W2, Wt2, 512, 256, 512, i - 229376);
  else if (i < 393216)     convW(W3, Wt3, 256, 128, 256, i - 360448);
  else if (i < 401408)     convW(W4, Wt4, 128, 64, 128, i - 393216);
}

// ---------------- per-layer GEMM: A (LDS, [64][K+8]) x Wt[N][K] (global/L2) ----------
// 8 waves; wave w owns col-tiles {w + j*8, j < NCT}. Output -> LDS [64][N+8], ReLU.
template<int K, int N, int NCT>
__device__ __forceinline__ void mlp_layer(const __bf16* __restrict__ Wt,
                                          const float* __restrict__ bias,
                                          const __bf16* Ain, __bf16* Aout,
                                          int w, int lane) {
  constexpr int LDA = K + 8, LDO = N + 8;
  const int lrow = lane & 15;
  const int kg = (lane >> 4) * 8;

  f32x4 acc[NCT][4];
  #pragma unroll
  for (int j = 0; j < NCT; ++j)
    #pragma unroll
    for (int m = 0; m < 4; ++m)
      #pragma unroll
      for (int i = 0; i < 4; ++i) acc[j][m][i] = 0.f;

  const __bf16* wp[NCT];
  #pragma unroll
  for (int j = 0; j < NCT; ++j)
    wp[j] = Wt + (size_t)((w + j * 8) * 16 + lrow) * K + kg;

  for (int k0 = 0; k0 < K; k0 += 32) {
    bf16x8 af[4];
    #pragma unroll
    for (int m = 0; m < 4; ++m)
      af[m] = *(const bf16x8*)(Ain + (m * 16 + lrow) * LDA + k0 + kg);
    bf16x8 bf[NCT];
    #pragma unroll
    for (int j = 0; j < NCT; ++j)
      bf[j] = *(const bf16x8*)(wp[j] + k0);
    #pragma unroll
    for (int j = 0; j < NCT; ++j)
      #pragma unroll
      for (int m = 0; m < 4; ++m)
        acc[j][m] = __builtin_amdgcn_mfma_f32_16x16x32_bf16(af[m], bf[j], acc[j][m], 0, 0, 0);
  }

  const int rbase = (lane >> 4) * 4;
  #pragma unroll
  for (int j = 0; j < NCT; ++j) {
    int col = (w + j * 8) * 16 + lrow;
    float bv = bias[col];
    #pragma unroll
    for (int m = 0; m < 4; ++m)
      #pragma unroll
      for (int i = 0; i < 4; ++i) {
        float v = acc[j][m][i] + bv;
        v = fmaxf(v, 0.f);
        Aout[(m * 16 + rbase + i) * LDO + col] = (__bf16)v;
      }
  }
}

// ---------------- fully fused: gather + FM + linear + 5-layer MLP + combine ---------
__global__ __launch_bounds__(512) void k_fused(
    const float* __restrict__ x_int,   // [B,13]
    const int*   __restrict__ x_cat,   // [B,26]
    const float* __restrict__ emb,     // [26,V,16]
    const float* __restrict__ lin,     // [26,V]
    const float* __restrict__ W_num,   // [13]
    const float* __restrict__ b_num,   // [1]
    const float* __restrict__ bias0,   // [1]
    const __bf16* __restrict__ Wt1, const float* __restrict__ b1,
    const __bf16* __restrict__ Wt2, const float* __restrict__ b2,
    const __bf16* __restrict__ Wt3, const float* __restrict__ b3,
    const __bf16* __restrict__ Wt4, const float* __restrict__ b4,
    const float* __restrict__ W5, const float* __restrict__ b5,
    float* __restrict__ out) {
  // LDS layout (125184 B total):
  //   A0 @ 0      : 64 x 456 bf16 (deep_in) -> 64x264 (h2) -> 64x72 (h4)   58368 B
  //   A1 @ 58368  : 64 x 520 bf16 (h1) -> 64x136 (h3)                      66560 B
  //   s_idx aliases A1 head (dead before first A1 write)                    6656 B
  //   s_part @ 124928 : 64 f32                                               256 B
  __shared__ __align__(16) char smem[125184];
  __bf16* A0 = (__bf16*)smem;
  __bf16* A1 = (__bf16*)(smem + 58368);
  int* s_idx = (int*)(smem + 58368);
  float* s_part = (float*)(smem + 124928);

  const int t = threadIdx.x;
  const int row0 = blockIdx.x * 64;
  const int w = t >> 6, lane = t & 63;

  // ---- stage categorical indices ----
  for (int i = t; i < 64 * NFEAT; i += 512) {
    int r = i / NFEAT, f = i - r * NFEAT;
    s_idx[i] = x_cat[(size_t)(row0 + r) * NFEAT + f];
  }
  __syncthreads();

  // ---- gather + FM + linear; build deep_in in LDS ----
  const float pbias = bias0[0] + b_num[0];
  #pragma unroll
  for (int pp = 0; pp < 2; ++pp) {
    const int p = t + pp * 512;
    const int r = p >> 4, d = p & 15;
    float sum = 0.f, sumsq = 0.f;
    #pragma unroll
    for (int f = 0; f < NFEAT; ++f) {
      int idx = s_idx[r * NFEAT + f];
      float e = emb[((size_t)f * VOCAB + idx) * 16 + d];
      sum += e; sumsq += e * e;
      A0[r * 456 + f * 16 + d] = (__bf16)e;
    }
    float xv = (d < 13) ? x_int[(size_t)(row0 + r) * 13 + d] : 0.f;
    A0[r * 456 + 416 + d] = (__bf16)xv;
    A0[r * 456 + 432 + d] = (__bf16)0.f;

    float lin_s = lin[(size_t)d * VOCAB + s_idx[r * NFEAT + d]];
    if (d < NFEAT - 16)
      lin_s += lin[(size_t)(d + 16) * VOCAB + s_idx[r * NFEAT + d + 16]];
    float lin_num = (d < 13) ? xv * W_num[d] : 0.f;

    float red = 0.5f * (sum * sum - sumsq) + lin_s + lin_num;
    #pragma unroll
    for (int off = 1; off < 16; off <<= 1) red += __shfl_xor(red, off, 16);
    if (d == 0) s_part[r] = red + pbias;
  }
  __syncthreads();

  // ---- MLP: ping-pong A0 <-> A1, weights streamed from L2 ----
  mlp_layer<448, 512, 4>(Wt1, b1, A0, A1, w, lane);
  __syncthreads();
  mlp_layer<512, 256, 2>(Wt2, b2, A1, A0, w, lane);
  __syncthreads();
  mlp_layer<256, 128, 1>(Wt3, b3, A0, A1, w, lane);
  __syncthreads();
  if (w < 4) mlp_layer<128, 64, 1>(Wt4, b4, A1, A0, w, lane);
  __syncthreads();

  // ---- final 64->1 dot + combine ----
  {
    const int r = t >> 3, g = t & 7;
    bf16x8 hv = *(const bf16x8*)(A0 + r * 72 + g * 8);
    float s = 0.f;
    #pragma unroll
    for (int i = 0; i < 8; ++i) s += (float)hv[i] * W5[g * 8 + i];
    #pragma unroll
    for (int off = 1; off < 8; off <<= 1) s += __shfl_xor(s, off, 8);
    if (g == 0) out[row0 + r] = s + b5[0] + s_part[r];
  }
}

extern "C" void kernel_launch(void* const* d_in, const int* in_sizes, int n_in,
                              void* d_out, int out_size, void* d_ws, size_t ws_size,
                              hipStream_t stream) {
  const float* x_int = (const float*)d_in[0];
  const int*   x_cat = (const int*)d_in[1];
  const float* emb   = (const float*)d_in[2];
  const float* lin   = (const float*)d_in[3];
  const float* W_num = (const float*)d_in[4];
  const float* b_num = (const float*)d_in[5];
  const float* bias  = (const float*)d_in[6];
  const float* W1 = (const float*)d_in[7];  const float* b1 = (const float*)d_in[8];
  const float* W2 = (const float*)d_in[9];  const float* b2 = (const float*)d_in[10];
  const float* W3 = (const float*)d_in[11]; const float* b3 = (const float*)d_in[12];
  const float* W4 = (const float*)d_in[13]; const float* b4 = (const float*)d_in[14];
  const float* W5 = (const float*)d_in[15]; const float* b5 = (const float*)d_in[16];
  float* out = (float*)d_out;

  char* ws = (char*)d_ws;
  __bf16* Wt1 = (__bf16*)(ws);            // [512][448] = 458752 B
  __bf16* Wt2 = (__bf16*)(ws + 458752);   // [256][512] = 262144 B
  __bf16* Wt3 = (__bf16*)(ws + 720896);   // [128][256] =  65536 B
  __bf16* Wt4 = (__bf16*)(ws + 786432);   // [64][128]  =  16384 B

  k_convAll<<<1568, 256, 0, stream>>>(W1, W2, W3, W4, Wt1, Wt2, Wt3, Wt4);

  k_fused<<<NROWS / 64, 512, 0, stream>>>(x_int, x_cat, emb, lin, W_num, b_num, bias,
                                          Wt1, b1, Wt2, b2, Wt3, b3, Wt4, b4, W5, b5,
                                          out);
}

// Round 3
// 51.180 us; speedup vs baseline: 1.9822x; 1.0350x over previous
//
#include <hip/hip_runtime.h>
#include <hip/hip_bf16.h>
#include <stdint.h>

typedef __bf16 bf16x8 __attribute__((ext_vector_type(8)));
typedef float  f32x4  __attribute__((ext_vector_type(4)));

#define NROWS 16384
#define NFEAT 26
#define VOCAB 100000

// ---------------- weight convert via LDS tile transpose ----------------
// W[K][N] fp32 (row-major) -> Wt[N][Kpad] bf16, zero-padded K->Kpad.
// Each block: 32x32 tile; coalesced read (along n), coalesced write (along k).
__device__ __forceinline__ void transpose_tile(const float* __restrict__ W,
                                               __bf16* __restrict__ Wt,
                                               int K, int N, int Kpad,
                                               int kt, int nt, int t) {
  __shared__ float tile[32][33];
  const int tx = t & 31, ty = t >> 5;           // 32 x 8
  const int k0 = kt * 32, n0 = nt * 32;
  #pragma unroll
  for (int j = 0; j < 4; ++j) {
    int k = k0 + ty + j * 8;
    tile[ty + j * 8][tx] = (k < K) ? W[(size_t)k * N + n0 + tx] : 0.f;
  }
  __syncthreads();
  #pragma unroll
  for (int j = 0; j < 4; ++j) {
    int n = n0 + ty + j * 8;
    Wt[(size_t)n * Kpad + k0 + tx] = (__bf16)tile[tx][ty + j * 8];
  }
}

__global__ __launch_bounds__(256) void k_convAll(
    const float* __restrict__ W1, const float* __restrict__ W2,
    const float* __restrict__ W3, const float* __restrict__ W4,
    __bf16* __restrict__ Wt1, __bf16* __restrict__ Wt2,
    __bf16* __restrict__ Wt3, __bf16* __restrict__ Wt4) {
  const int b = blockIdx.x, t = threadIdx.x;
  if (b < 224)       { int i = b;        transpose_tile(W1, Wt1, 429, 512, 448, i % 14, i / 14, t); }
  else if (b < 352)  { int i = b - 224;  transpose_tile(W2, Wt2, 512, 256, 512, i % 16, i / 16, t); }
  else if (b < 384)  { int i = b - 352;  transpose_tile(W3, Wt3, 256, 128, 256, i % 8,  i / 8,  t); }
  else               { int i = b - 384;  transpose_tile(W4, Wt4, 128,  64, 128, i % 4,  i / 4,  t); }
}

// ---------------- per-layer GEMM: A (LDS, [64][K+8]) x Wt[N][K] (global) ----------
// Wave w owns col-tiles {w + j*WS, j < NCT}. Output -> LDS [64][N+8], ReLU.
template<int K, int N, int NCT, int WS>
__device__ __forceinline__ void mlp_layer(const __bf16* __restrict__ Wt,
                                          const float* __restrict__ bias,
                                          const __bf16* Ain, __bf16* Aout,
                                          int w, int lane) {
  constexpr int LDA = K + 8, LDO = N + 8;
  const int lrow = lane & 15;
  const int kg = (lane >> 4) * 8;

  f32x4 acc[NCT][4];
  #pragma unroll
  for (int j = 0; j < NCT; ++j)
    #pragma unroll
    for (int m = 0; m < 4; ++m)
      #pragma unroll
      for (int i = 0; i < 4; ++i) acc[j][m][i] = 0.f;

  const __bf16* wp[NCT];
  #pragma unroll
  for (int j = 0; j < NCT; ++j)
    wp[j] = Wt + (size_t)((w + j * WS) * 16 + lrow) * K + kg;

  for (int k0 = 0; k0 < K; k0 += 32) {
    bf16x8 af[4];
    #pragma unroll
    for (int m = 0; m < 4; ++m)
      af[m] = *(const bf16x8*)(Ain + (m * 16 + lrow) * LDA + k0 + kg);
    bf16x8 bf[NCT];
    #pragma unroll
    for (int j = 0; j < NCT; ++j)
      bf[j] = *(const bf16x8*)(wp[j] + k0);
    #pragma unroll
    for (int j = 0; j < NCT; ++j)
      #pragma unroll
      for (int m = 0; m < 4; ++m)
        acc[j][m] = __builtin_amdgcn_mfma_f32_16x16x32_bf16(af[m], bf[j], acc[j][m], 0, 0, 0);
  }

  const int rbase = (lane >> 4) * 4;
  #pragma unroll
  for (int j = 0; j < NCT; ++j) {
    int col = (w + j * WS) * 16 + lrow;
    float bv = bias[col];
    #pragma unroll
    for (int m = 0; m < 4; ++m)
      #pragma unroll
      for (int i = 0; i < 4; ++i) {
        float v = acc[j][m][i] + bv;
        v = fmaxf(v, 0.f);
        Aout[(m * 16 + rbase + i) * LDO + col] = (__bf16)v;
      }
  }
}

// ---------------- fully fused: gather + FM + linear + 5-layer MLP + combine -------
__global__ __launch_bounds__(1024) void k_fused(
    const float* __restrict__ x_int,   // [B,13]
    const int*   __restrict__ x_cat,   // [B,26]
    const float* __restrict__ emb,     // [26,V,16]
    const float* __restrict__ lin,     // [26,V]
    const float* __restrict__ W_num,   // [13]
    const float* __restrict__ b_num,   // [1]
    const float* __restrict__ bias0,   // [1]
    const __bf16* __restrict__ Wt1, const float* __restrict__ b1,
    const __bf16* __restrict__ Wt2, const float* __restrict__ b2,
    const __bf16* __restrict__ Wt3, const float* __restrict__ b3,
    const __bf16* __restrict__ Wt4, const float* __restrict__ b4,
    const float* __restrict__ W5, const float* __restrict__ b5,
    float* __restrict__ out) {
  // LDS (125184 B): A0 @0 : 64x456 bf16 (58368 B); A1 @58368 : 64x520 bf16 (66560 B);
  // s_idx aliases A1 head; s_part @124928 : 64 f32.
  __shared__ __align__(16) char smem[125184];
  __bf16* A0 = (__bf16*)smem;
  __bf16* A1 = (__bf16*)(smem + 58368);
  int* s_idx = (int*)(smem + 58368);
  float* s_part = (float*)(smem + 124928);

  const int t = threadIdx.x;
  const int row0 = blockIdx.x * 64;
  const int w = t >> 6, lane = t & 63;

  // ---- stage categorical indices ----
  for (int i = t; i < 64 * NFEAT; i += 1024) {
    int r = i / NFEAT, f = i - r * NFEAT;
    s_idx[i] = x_cat[(size_t)(row0 + r) * NFEAT + f];
  }
  __syncthreads();

  // ---- gather + FM + linear; build deep_in in LDS ----
  {
    const float pbias = bias0[0] + b_num[0];
    const int r = t >> 4, d = t & 15;
    float sum = 0.f, sumsq = 0.f;
    #pragma unroll
    for (int f = 0; f < NFEAT; ++f) {
      int idx = s_idx[r * NFEAT + f];
      float e = emb[((size_t)f * VOCAB + idx) * 16 + d];
      sum += e; sumsq += e * e;
      A0[r * 456 + f * 16 + d] = (__bf16)e;
    }
    float xv = (d < 13) ? x_int[(size_t)(row0 + r) * 13 + d] : 0.f;
    A0[r * 456 + 416 + d] = (__bf16)xv;
    A0[r * 456 + 432 + d] = (__bf16)0.f;

    float lin_s = lin[(size_t)d * VOCAB + s_idx[r * NFEAT + d]];
    if (d < NFEAT - 16)
      lin_s += lin[(size_t)(d + 16) * VOCAB + s_idx[r * NFEAT + d + 16]];
    float lin_num = (d < 13) ? xv * W_num[d] : 0.f;

    float red = 0.5f * (sum * sum - sumsq) + lin_s + lin_num;
    #pragma unroll
    for (int off = 1; off < 16; off <<= 1) red += __shfl_xor(red, off, 16);
    if (d == 0) s_part[r] = red + pbias;
  }
  __syncthreads();

  // ---- MLP: ping-pong A0 <-> A1, weights streamed from L2 ----
  mlp_layer<448, 512, 2, 16>(Wt1, b1, A0, A1, w, lane);
  __syncthreads();
  mlp_layer<512, 256, 1, 16>(Wt2, b2, A1, A0, w, lane);
  __syncthreads();
  if (w < 8) mlp_layer<256, 128, 1, 8>(Wt3, b3, A0, A1, w, lane);
  __syncthreads();
  if (w < 4) mlp_layer<128, 64, 1, 4>(Wt4, b4, A1, A0, w, lane);
  __syncthreads();

  // ---- final 64->1 dot + combine ----
  {
    const int r = t >> 4, g = t & 15;
    float s = 0.f;
    #pragma unroll
    for (int i = 0; i < 4; ++i)
      s += (float)A0[r * 72 + g * 4 + i] * W5[g * 4 + i];
    #pragma unroll
    for (int off = 1; off < 16; off <<= 1) s += __shfl_xor(s, off, 16);
    if (g == 0) out[row0 + r] = s + b5[0] + s_part[r];
  }
}

extern "C" void kernel_launch(void* const* d_in, const int* in_sizes, int n_in,
                              void* d_out, int out_size, void* d_ws, size_t ws_size,
                              hipStream_t stream) {
  const float* x_int = (const float*)d_in[0];
  const int*   x_cat = (const int*)d_in[1];
  const float* emb   = (const float*)d_in[2];
  const float* lin   = (const float*)d_in[3];
  const float* W_num = (const float*)d_in[4];
  const float* b_num = (const float*)d_in[5];
  const float* bias  = (const float*)d_in[6];
  const float* W1 = (const float*)d_in[7];  const float* b1 = (const float*)d_in[8];
  const float* W2 = (const float*)d_in[9];  const float* b2 = (const float*)d_in[10];
  const float* W3 = (const float*)d_in[11]; const float* b3 = (const float*)d_in[12];
  const float* W4 = (const float*)d_in[13]; const float* b4 = (const float*)d_in[14];
  const float* W5 = (const float*)d_in[15]; const float* b5 = (const float*)d_in[16];
  float* out = (float*)d_out;

  char* ws = (char*)d_ws;
  __bf16* Wt1 = (__bf16*)(ws);            // [512][448] = 458752 B
  __bf16* Wt2 = (__bf16*)(ws + 458752);   // [256][512] = 262144 B
  __bf16* Wt3 = (__bf16*)(ws + 720896);   // [128][256] =  65536 B
  __bf16* Wt4 = (__bf16*)(ws + 786432);   // [64][128]  =  16384 B

  k_convAll<<<392, 256, 0, stream>>>(W1, W2, W3, W4, Wt1, Wt2, Wt3, Wt4);

  k_fused<<<NROWS / 64, 1024, 0, stream>>>(x_int, x_cat, emb, lin, W_num, b_num, bias,
                                           Wt1, b1, Wt2, b2, Wt3, b3, Wt4, b4, W5, b5,
                                           out);
}

// Round 4
// 46.459 us; speedup vs baseline: 2.1836x; 1.1016x over previous
//
#include <hip/hip_runtime.h>
#include <hip/hip_bf16.h>
#include <stdint.h>

typedef __bf16 bf16x8 __attribute__((ext_vector_type(8)));
typedef float  f32x4  __attribute__((ext_vector_type(4)));

#define NROWS 16384
#define NFEAT 26
#define VOCAB 100000

// ---------------- per-layer GEMM: A (LDS, [rows][KPAD+8] bf16) x W[KREAL][N] fp32 ----
// Wave w owns col-tiles {w + j*WS, j < NCT}. Output -> LDS [rows][N+8] bf16, ReLU.
// Weights are read DIRECTLY from the read-only fp32 input (no pre-convert kernel):
// clean lines -> every XCD's L2 keeps a shared copy; no cross-XCD dirty-read path.
template<int KPAD, int KREAL, int N, int NCT, int WS>
__device__ __forceinline__ void mlp_layer(const float* __restrict__ W,
                                          const float* __restrict__ bias,
                                          const __bf16* Ain, __bf16* Aout,
                                          int w, int lane) {
  constexpr int LDA = KPAD + 8, LDO = N + 8;
  constexpr int KSAFE = (KREAL / 32) * 32;   // k-steps below this need no clamp
  const int lrow = lane & 15;
  const int kg = (lane >> 4) * 8;

  f32x4 acc[NCT][4];
  #pragma unroll
  for (int j = 0; j < NCT; ++j)
    #pragma unroll
    for (int m = 0; m < 4; ++m)
      #pragma unroll
      for (int i = 0; i < 4; ++i) acc[j][m][i] = 0.f;

  int col[NCT];
  #pragma unroll
  for (int j = 0; j < NCT; ++j) col[j] = (w + j * WS) * 16 + lrow;

  auto step = [&](int k0, bool clamp) {
    bf16x8 af[4];
    #pragma unroll
    for (int m = 0; m < 4; ++m)
      af[m] = *(const bf16x8*)(Ain + (m * 16 + lrow) * LDA + k0 + kg);
    #pragma unroll
    for (int j = 0; j < NCT; ++j) {
      bf16x8 bf;
      #pragma unroll
      for (int i = 0; i < 8; ++i) {
        int k = k0 + kg + i;
        float v = (!clamp || k < KREAL) ? W[(size_t)k * N + col[j]] : 0.f;
        bf[i] = (__bf16)v;
      }
      #pragma unroll
      for (int m = 0; m < 4; ++m)
        acc[j][m] = __builtin_amdgcn_mfma_f32_16x16x32_bf16(af[m], bf, acc[j][m], 0, 0, 0);
    }
  };

  for (int k0 = 0; k0 < KSAFE; k0 += 32) step(k0, false);
  if constexpr (KSAFE < KPAD) step(KSAFE, true);

  const int rbase = (lane >> 4) * 4;
  #pragma unroll
  for (int j = 0; j < NCT; ++j) {
    float bv = bias[col[j]];
    #pragma unroll
    for (int m = 0; m < 4; ++m)
      #pragma unroll
      for (int i = 0; i < 4; ++i) {
        float v = acc[j][m][i] + bv;
        v = fmaxf(v, 0.f);
        Aout[(m * 16 + rbase + i) * LDO + col[j]] = (__bf16)v;
      }
  }
}

// ---------------- fully fused: gather + FM + linear + 5-layer MLP + combine -------
__global__ __launch_bounds__(1024) void k_fused(
    const float* __restrict__ x_int,   // [B,13]
    const int*   __restrict__ x_cat,   // [B,26]
    const float* __restrict__ emb,     // [26,V,16]
    const float* __restrict__ lin,     // [26,V]
    const float* __restrict__ W_num,   // [13]
    const float* __restrict__ b_num,   // [1]
    const float* __restrict__ bias0,   // [1]
    const float* __restrict__ W1, const float* __restrict__ b1,
    const float* __restrict__ W2, const float* __restrict__ b2,
    const float* __restrict__ W3, const float* __restrict__ b3,
    const float* __restrict__ W4, const float* __restrict__ b4,
    const float* __restrict__ W5, const float* __restrict__ b5,
    float* __restrict__ out) {
  // LDS (125184 B): A0 @0 : 64x456 bf16 (58368 B); A1 @58368 : 64x520 bf16 (66560 B);
  // s_idx aliases A1 head (dead before first A1 write); s_part @124928 : 64 f32.
  __shared__ __align__(16) char smem[125184];
  __bf16* A0 = (__bf16*)smem;
  __bf16* A1 = (__bf16*)(smem + 58368);
  int* s_idx = (int*)(smem + 58368);
  float* s_part = (float*)(smem + 124928);

  const int t = threadIdx.x;
  const int row0 = blockIdx.x * 64;
  const int w = t >> 6, lane = t & 63;

  // ---- stage categorical indices ----
  for (int i = t; i < 64 * NFEAT; i += 1024) {
    int r = i / NFEAT, f = i - r * NFEAT;
    s_idx[i] = x_cat[(size_t)(row0 + r) * NFEAT + f];
  }
  __syncthreads();

  // ---- gather + FM + linear; build deep_in in LDS ----
  {
    const float pbias = bias0[0] + b_num[0];
    const int r = t >> 4, d = t & 15;
    float sum = 0.f, sumsq = 0.f;
    #pragma unroll
    for (int f = 0; f < NFEAT; ++f) {
      int idx = s_idx[r * NFEAT + f];
      float e = emb[((size_t)f * VOCAB + idx) * 16 + d];
      sum += e; sumsq += e * e;
      A0[r * 456 + f * 16 + d] = (__bf16)e;
    }
    float xv = (d < 13) ? x_int[(size_t)(row0 + r) * 13 + d] : 0.f;
    A0[r * 456 + 416 + d] = (__bf16)xv;
    A0[r * 456 + 432 + d] = (__bf16)0.f;

    float lin_s = lin[(size_t)d * VOCAB + s_idx[r * NFEAT + d]];
    if (d < NFEAT - 16)
      lin_s += lin[(size_t)(d + 16) * VOCAB + s_idx[r * NFEAT + d + 16]];
    float lin_num = (d < 13) ? xv * W_num[d] : 0.f;

    float red = 0.5f * (sum * sum - sumsq) + lin_s + lin_num;
    #pragma unroll
    for (int off = 1; off < 16; off <<= 1) red += __shfl_xor(red, off, 16);
    if (d == 0) s_part[r] = red + pbias;
  }
  __syncthreads();

  // ---- MLP: ping-pong A0 <-> A1, fp32 weights streamed from L2 (read-only) ----
  mlp_layer<448, 429, 512, 2, 16>(W1, b1, A0, A1, w, lane);
  __syncthreads();
  mlp_layer<512, 512, 256, 1, 16>(W2, b2, A1, A0, w, lane);
  __syncthreads();
  if (w < 8) mlp_layer<256, 256, 128, 1, 8>(W3, b3, A0, A1, w, lane);
  __syncthreads();
  if (w < 4) mlp_layer<128, 128, 64, 1, 4>(W4, b4, A1, A0, w, lane);
  __syncthreads();

  // ---- final 64->1 dot + combine ----
  {
    const int r = t >> 4, g = t & 15;
    float s = 0.f;
    #pragma unroll
    for (int i = 0; i < 4; ++i)
      s += (float)A0[r * 72 + g * 4 + i] * W5[g * 4 + i];
    #pragma unroll
    for (int off = 1; off < 16; off <<= 1) s += __shfl_xor(s, off, 16);
    if (g == 0) out[row0 + r] = s + b5[0] + s_part[r];
  }
}

extern "C" void kernel_launch(void* const* d_in, const int* in_sizes, int n_in,
                              void* d_out, int out_size, void* d_ws, size_t ws_size,
                              hipStream_t stream) {
  const float* x_int = (const float*)d_in[0];
  const int*   x_cat = (const int*)d_in[1];
  const float* emb   = (const float*)d_in[2];
  const float* lin   = (const float*)d_in[3];
  const float* W_num = (const float*)d_in[4];
  const float* b_num = (const float*)d_in[5];
  const float* bias  = (const float*)d_in[6];
  const float* W1 = (const float*)d_in[7];  const float* b1 = (const float*)d_in[8];
  const float* W2 = (const float*)d_in[9];  const float* b2 = (const float*)d_in[10];
  const float* W3 = (const float*)d_in[11]; const float* b3 = (const float*)d_in[12];
  const float* W4 = (const float*)d_in[13]; const float* b4 = (const float*)d_in[14];
  const float* W5 = (const float*)d_in[15]; const float* b5 = (const float*)d_in[16];
  float* out = (float*)d_out;

  k_fused<<<NROWS / 64, 1024, 0, stream>>>(x_int, x_cat, emb, lin, W_num, b_num, bias,
                                           W1, b1, W2, b2, W3, b3, W4, b4, W5, b5,
                                           out);
}

// Round 5
// 44.175 us; speedup vs baseline: 2.2965x; 1.0517x over previous
//
#include <hip/hip_runtime.h>
#include <hip/hip_bf16.h>
#include <stdint.h>

typedef __bf16 bf16x8 __attribute__((ext_vector_type(8)));
typedef __bf16 bf16x4 __attribute__((ext_vector_type(4)));
typedef float  f32x4  __attribute__((ext_vector_type(4)));

#define NROWS 16384
#define NFEAT 26
#define VOCAB 100000

// ---------------- per-layer GEMM (layers 2-4): A (LDS) x W[KREAL][N] fp32 ----------
template<int KPAD, int KREAL, int N, int NCT, int WS>
__device__ __forceinline__ void mlp_layer(const float* __restrict__ W,
                                          const float* __restrict__ bias,
                                          const __bf16* Ain, __bf16* Aout,
                                          int w, int lane) {
  constexpr int LDA = KPAD + 8, LDO = N + 8;
  const int lrow = lane & 15;
  const int kg = (lane >> 4) * 8;

  f32x4 acc[NCT][4];
  #pragma unroll
  for (int j = 0; j < NCT; ++j)
    #pragma unroll
    for (int m = 0; m < 4; ++m)
      #pragma unroll
      for (int i = 0; i < 4; ++i) acc[j][m][i] = 0.f;

  int col[NCT];
  #pragma unroll
  for (int j = 0; j < NCT; ++j) col[j] = (w + j * WS) * 16 + lrow;

  for (int k0 = 0; k0 < KREAL; k0 += 32) {
    bf16x8 af[4];
    #pragma unroll
    for (int m = 0; m < 4; ++m)
      af[m] = *(const bf16x8*)(Ain + (m * 16 + lrow) * LDA + k0 + kg);
    #pragma unroll
    for (int j = 0; j < NCT; ++j) {
      bf16x8 bw;
      #pragma unroll
      for (int i = 0; i < 8; ++i)
        bw[i] = (__bf16)W[(size_t)(k0 + kg + i) * N + col[j]];
      #pragma unroll
      for (int m = 0; m < 4; ++m)
        acc[j][m] = __builtin_amdgcn_mfma_f32_16x16x32_bf16(af[m], bw, acc[j][m], 0, 0, 0);
    }
  }

  const int rbase = (lane >> 4) * 4;
  #pragma unroll
  for (int j = 0; j < NCT; ++j) {
    float bv = bias[col[j]];
    #pragma unroll
    for (int m = 0; m < 4; ++m)
      #pragma unroll
      for (int i = 0; i < 4; ++i) {
        float v = acc[j][m][i] + bv;
        v = fmaxf(v, 0.f);
        Aout[(m * 16 + rbase + i) * LDO + col[j]] = (__bf16)v;
      }
  }
}

// ---------------- fused: pipelined {gather || layer-1} + layers 2-5 + combine -------
__global__ __launch_bounds__(1024) void k_fused(
    const float* __restrict__ x_int,   // [B,13]
    const int*   __restrict__ x_cat,   // [B,26]
    const float* __restrict__ emb,     // [26,V,16]
    const float* __restrict__ lin,     // [26,V]
    const float* __restrict__ W_num,   // [13]
    const float* __restrict__ b_num,   // [1]
    const float* __restrict__ bias0,   // [1]
    const float* __restrict__ W1, const float* __restrict__ b1,
    const float* __restrict__ W2, const float* __restrict__ b2,
    const float* __restrict__ W3, const float* __restrict__ b3,
    const float* __restrict__ W4, const float* __restrict__ b4,
    const float* __restrict__ W5, const float* __restrict__ b5,
    float* __restrict__ out) {
  // LDS (125184 B): A0 @0 : 64x456 bf16; A1 @58368 : 64x520 bf16 (s_idx aliases
  // A1 head; A1 first written in layer-1 epilogue, after last s_idx read);
  // s_part @124928 : 64 f32.
  __shared__ __align__(16) char smem[125184];
  __bf16* A0 = (__bf16*)smem;
  __bf16* A1 = (__bf16*)(smem + 58368);
  int* s_idx = (int*)(smem + 58368);
  float* s_part = (float*)(smem + 124928);

  const int t = threadIdx.x;
  const int row0 = blockIdx.x * 64;
  const int w = t >> 6, lane = t & 63;
  const int lrow = lane & 15, kg = (lane >> 4) * 8;

  // ---- stage categorical indices ----
  for (int i = t; i < 64 * NFEAT; i += 1024) {
    int r = i / NFEAT, f = i - r * NFEAT;
    s_idx[i] = x_cat[(size_t)(row0 + r) * NFEAT + f];
  }
  __syncthreads();

  const int r = t >> 4, d = t & 15;
  const int g = d >> 2, q = d & 3;   // feature-group (0..3), dim-quad (0..3)

  // ---- linear terms (issued early, consumed after layer-1 loop) ----
  float lin_s = 0.f;
  if (d < 13) {
    lin_s = lin[(size_t)d * VOCAB + s_idx[r * NFEAT + d]]
          + lin[(size_t)(d + 13) * VOCAB + s_idx[r * NFEAT + d + 13]]
          + x_int[(size_t)(row0 + r) * 13 + d] * W_num[d];
  }
  // x_int values for the chunk-6 LDS tail (cols 416..447), threads d=8..11
  float xv[4] = {0.f, 0.f, 0.f, 0.f};
  if (d >= 8 && d < 12) {
    int base = (d - 8) * 4;
    #pragma unroll
    for (int i = 0; i < 4; ++i)
      if (base + i < 13) xv[i] = x_int[(size_t)(row0 + r) * 13 + base + i];
  }

  // ---- layer-1 accumulators (NCT=2, wave-stride 16 -> cols w*16.. , (w+16)*16..) --
  f32x4 acc[2][4];
  #pragma unroll
  for (int j = 0; j < 2; ++j)
    #pragma unroll
    for (int m = 0; m < 4; ++m)
      #pragma unroll
      for (int i = 0; i < 4; ++i) acc[j][m][i] = 0.f;
  const int colL1[2] = { w * 16 + lrow, (w + 16) * 16 + lrow };

  // ---- pipelined gather || layer-1: 7 chunks of 64 K-cols (4 features) ----
  float fsum[4] = {0.f,0.f,0.f,0.f}, fsq[4] = {0.f,0.f,0.f,0.f};
  f32x4 cur;
  {
    int idx = s_idx[r * NFEAT + g];
    cur = *(const f32x4*)(emb + ((size_t)g * VOCAB + idx) * 16 + q * 4);
  }

  #pragma unroll
  for (int c = 0; c < 7; ++c) {
    // issue next chunk's gather (overlaps this chunk's MFMA below)
    f32x4 nxt;
    if (c < 6) {
      int fc = 4 * (c + 1) + g;
      if (fc < NFEAT) {
        int idx = s_idx[r * NFEAT + fc];
        nxt = *(const f32x4*)(emb + ((size_t)fc * VOCAB + idx) * 16 + q * 4);
      }
    }
    // consume current chunk -> LDS + FM partials
    const int colbase = c * 64 + g * 16 + q * 4;
    if (4 * c + g < NFEAT) {
      bf16x4 pk;
      #pragma unroll
      for (int i = 0; i < 4; ++i) {
        fsum[i] += cur[i]; fsq[i] += cur[i] * cur[i];
        pk[i] = (__bf16)cur[i];
      }
      *(bf16x4*)(A0 + r * 456 + colbase) = pk;
    } else {                       // c==6, d>=8: x_int + zero pad
      bf16x4 pk;
      #pragma unroll
      for (int i = 0; i < 4; ++i) pk[i] = (__bf16)xv[i];
      *(bf16x4*)(A0 + r * 456 + colbase) = pk;
    }
    // raw barrier (NO vmcnt drain -> prefetch stays in flight)
    asm volatile("s_waitcnt lgkmcnt(0)" ::: "memory");
    __builtin_amdgcn_s_barrier();
    asm volatile("" ::: "memory");
    // layer-1 MFMA over this chunk's 2 K-steps, W1 streamed from L2
    #pragma unroll
    for (int ks = 0; ks < 2; ++ks) {
      const int k0 = c * 64 + ks * 32;
      bf16x8 af[4];
      #pragma unroll
      for (int m = 0; m < 4; ++m)
        af[m] = *(const bf16x8*)(A0 + (m * 16 + lrow) * 456 + k0 + kg);
      #pragma unroll
      for (int j = 0; j < 2; ++j) {
        bf16x8 bw;
        #pragma unroll
        for (int i = 0; i < 8; ++i) {
          int k = k0 + kg + i;
          float v;
          if (c < 6) v = W1[(size_t)k * 512 + colL1[j]];
          else       v = (k < 429) ? W1[(size_t)k * 512 + colL1[j]] : 0.f;
          bw[i] = (__bf16)v;
        }
        #pragma unroll
        for (int m = 0; m < 4; ++m)
          acc[j][m] = __builtin_amdgcn_mfma_f32_16x16x32_bf16(af[m], bw, acc[j][m], 0, 0, 0);
      }
    }
    cur = nxt;
  }

  // ---- layer-1 epilogue: bias + ReLU -> A1 (overwrites s_idx alias: safe now) ----
  {
    const int rbase = (lane >> 4) * 4;
    #pragma unroll
    for (int j = 0; j < 2; ++j) {
      float bv = b1[colL1[j]];
      #pragma unroll
      for (int m = 0; m < 4; ++m)
        #pragma unroll
        for (int i = 0; i < 4; ++i) {
          float v = acc[j][m][i] + bv;
          v = fmaxf(v, 0.f);
          A1[(m * 16 + rbase + i) * 520 + colL1[j]] = (__bf16)v;
        }
    }
  }

  // ---- FM + linear combine -> s_part ----
  {
    #pragma unroll
    for (int i = 0; i < 4; ++i) {
      fsum[i] += __shfl_xor(fsum[i], 4); fsq[i] += __shfl_xor(fsq[i], 4);
      fsum[i] += __shfl_xor(fsum[i], 8); fsq[i] += __shfl_xor(fsq[i], 8);
    }
    float fmq = 0.f;
    #pragma unroll
    for (int i = 0; i < 4; ++i) fmq += fsum[i] * fsum[i] - fsq[i];
    fmq += __shfl_xor(fmq, 1);
    fmq += __shfl_xor(fmq, 2);     // full FM, replicated over d
    float linred = lin_s;
    #pragma unroll
    for (int off = 1; off < 16; off <<= 1) linred += __shfl_xor(linred, off, 16);
    if (d == 0) s_part[r] = 0.5f * fmq + linred + bias0[0] + b_num[0];
  }
  __syncthreads();

  // ---- layers 2-4 ----
  mlp_layer<512, 512, 256, 1, 16>(W2, b2, A1, A0, w, lane);
  __syncthreads();
  if (w < 8) mlp_layer<256, 256, 128, 1, 8>(W3, b3, A0, A1, w, lane);
  __syncthreads();
  if (w < 4) mlp_layer<128, 128, 64, 1, 4>(W4, b4, A1, A0, w, lane);
  __syncthreads();

  // ---- final 64->1 dot + combine ----
  {
    const int rr = t >> 4, gg = t & 15;
    float s = 0.f;
    #pragma unroll
    for (int i = 0; i < 4; ++i)
      s += (float)A0[rr * 72 + gg * 4 + i] * W5[gg * 4 + i];
    #pragma unroll
    for (int off = 1; off < 16; off <<= 1) s += __shfl_xor(s, off, 16);
    if (gg == 0) out[row0 + rr] = s + b5[0] + s_part[rr];
  }
}

extern "C" void kernel_launch(void* const* d_in, const int* in_sizes, int n_in,
                              void* d_out, int out_size, void* d_ws, size_t ws_size,
                              hipStream_t stream) {
  const float* x_int = (const float*)d_in[0];
  const int*   x_cat = (const int*)d_in[1];
  const float* emb   = (const float*)d_in[2];
  const float* lin   = (const float*)d_in[3];
  const float* W_num = (const float*)d_in[4];
  const float* b_num = (const float*)d_in[5];
  const float* bias  = (const float*)d_in[6];
  const float* W1 = (const float*)d_in[7];  const float* b1 = (const float*)d_in[8];
  const float* W2 = (const float*)d_in[9];  const float* b2 = (const float*)d_in[10];
  const float* W3 = (const float*)d_in[11]; const float* b3 = (const float*)d_in[12];
  const float* W4 = (const float*)d_in[13]; const float* b4 = (const float*)d_in[14];
  const float* W5 = (const float*)d_in[15]; const float* b5 = (const float*)d_in[16];
  float* out = (float*)d_out;

  k_fused<<<NROWS / 64, 1024, 0, stream>>>(x_int, x_cat, emb, lin, W_num, b_num, bias,
                                           W1, b1, W2, b2, W3, b3, W4, b4, W5, b5,
                                           out);
}